// Round 7
// baseline (209.547 us; speedup 1.0000x reference)
//
#include <hip/hip_runtime.h>

// Mamba block forward. Round 7: scan with explicit double-buffered register
// batch prefetch (force ILP the compiler refused), float2 B-loads in pass A,
// DPP cross-lane reduction in pass B.
constexpr int B  = 2, L = 1024, DM = 512, DI = 1024, NST = 16, PW = 97;
constexpr int ML = B * L;                   // 2048 rows
constexpr int NCHUNK = 32, CL = L / NCHUNK; // 32 chunks x 32 steps
constexpr int NLANES = B * DI * NST;        // 32768 scan lanes

#define DEV_INLINE __device__ __forceinline__

typedef __attribute__((ext_vector_type(8))) short bf16x8;   // 8 bf16 (4 VGPRs)
typedef __attribute__((ext_vector_type(4))) float f32x4;    // 4 fp32 acc

DEV_INLINE float sigmoidf_(float x) { return 1.f / (1.f + __expf(-x)); }
DEV_INLINE unsigned short f2bf(float f) {
  unsigned int u = __float_as_uint(f);
  return (unsigned short)((u + 0x7FFFu + ((u >> 16) & 1u)) >> 16);  // RNE
}

#if __has_builtin(__builtin_amdgcn_exp2f)
#define EXP2F(x) __builtin_amdgcn_exp2f(x)
#else
#define EXP2F(x) exp2f(x)
#endif
#if __has_builtin(__builtin_amdgcn_sinf)
#define SINR(x) __builtin_amdgcn_sinf(x)   // sin(2*pi*x), x in revolutions
#define COSR(x) __builtin_amdgcn_cosf(x)
#else
#define SINR(x) __sinf((x) * 6.2831853f)
#define COSR(x) __cosf((x) * 6.2831853f)
#endif

// Taylor sin/cos (radians), valid |th| <~ 2 with <5e-5 error. Shares t2.
DEV_INLINE void sincos_poly(float th, float& s, float& c) {
  float t2 = th * th;
  float u = fmaf(t2, 2.7557319e-6f, -1.9841270e-4f);
  u = fmaf(t2, u, 8.3333333e-3f);
  u = fmaf(t2, u, -0.16666667f);
  u = fmaf(t2, u, 1.f);
  s = th * u;
  float v = fmaf(t2, 2.4801587e-5f, -1.3888889e-3f);
  v = fmaf(t2, v, 4.1666667e-2f);
  v = fmaf(t2, v, -0.5f);
  c = fmaf(t2, v, 1.f);
}

// DPP 16-lane add-reduce helpers (quad_perm xor1, xor2, row_ror:4, row_ror:8)
template <int CTRL>
DEV_INLINE float dpp_add(float v) {
  int x = __builtin_amdgcn_update_dpp(0, __float_as_int(v), CTRL, 0xF, 0xF, true);
  return v + __int_as_float(x);
}

// ---------------------------------------------------------------------------
// f32 -> bf16 convert, 3 segments in one launch (x, in_proj_w, out_proj_w)
// ---------------------------------------------------------------------------
__global__ __launch_bounds__(256) void cvt3_k(
    const float* __restrict__ i0, unsigned short* __restrict__ o0, int n0,
    const float* __restrict__ i1, unsigned short* __restrict__ o1, int n1,
    const float* __restrict__ i2, unsigned short* __restrict__ o2, int n2) {
  int i = blockIdx.x * 256 + threadIdx.x;   // in float4 units
  const float* in; unsigned short* out; int off;
  if (i < n0)              { in = i0; out = o0; off = i; }
  else if (i < n0 + n1)    { in = i1; out = o1; off = i - n0; }
  else if (i < n0 + n1 + n2) { in = i2; out = o2; off = i - n0 - n1; }
  else return;
  float4 v = ((const float4*)in)[off];
  ((ushort4*)out)[off] = make_ushort4(f2bf(v.x), f2bf(v.y), f2bf(v.z), f2bf(v.w));
}

// ---------------------------------------------------------------------------
// bf16 MFMA GEMM, 64x64 tile, BK=64, 4 waves, XOR-swizzled LDS.
// ---------------------------------------------------------------------------
DEV_INLINE int swz(int row, int kb) { return (row << 7) + (kb ^ ((row & 7) << 4)); }

__global__ __launch_bounds__(256) void gemm_bf16_64(
    const short* __restrict__ A, const short* __restrict__ W,
    float* __restrict__ C, int M, int N, int K) {
  __shared__ char ldsb[16384];               // A [0,8K), W [8K,16K)
  const int tid = threadIdx.x;
  const int lane = tid & 63, wv = tid >> 6;
  const int bm = blockIdx.y * 64, bn = blockIdx.x * 64;

  f32x4 acc[4];
#pragma unroll
  for (int nb = 0; nb < 4; ++nb) acc[nb] = (f32x4){0.f, 0.f, 0.f, 0.f};

  for (int k0 = 0; k0 < K; k0 += 64) {
#pragma unroll
    for (int i = 0; i < 2; ++i) {
      int off = i * 4096 + tid * 16;
      int row = off >> 7, kb = off & 127;
      bf16x8 va = *(const bf16x8*)(A + (size_t)(bm + row) * K + k0 + (kb >> 1));
      bf16x8 vw = *(const bf16x8*)(W + (size_t)(bn + row) * K + k0 + (kb >> 1));
      *(bf16x8*)(ldsb + swz(row, kb)) = va;
      *(bf16x8*)(ldsb + 8192 + swz(row, kb)) = vw;
    }
    __syncthreads();
#pragma unroll
    for (int ks = 0; ks < 2; ++ks) {
      const int kb = ks * 64 + ((lane >> 4) << 4);
      bf16x8 af = *(const bf16x8*)(ldsb + swz(wv * 16 + (lane & 15), kb));
#pragma unroll
      for (int nb = 0; nb < 4; ++nb) {
        bf16x8 bfv = *(const bf16x8*)(ldsb + 8192 + swz(nb * 16 + (lane & 15), kb));
        acc[nb] = __builtin_amdgcn_mfma_f32_16x16x32_bf16(af, bfv, acc[nb], 0, 0, 0);
      }
    }
    __syncthreads();
  }
#pragma unroll
  for (int nb = 0; nb < 4; ++nb) {
    int col = bn + nb * 16 + (lane & 15);
    int row0 = bm + wv * 16 + ((lane >> 4) << 2);
#pragma unroll
    for (int j = 0; j < 4; ++j)
      C[(size_t)(row0 + j) * N + col] = acc[nb][j];
  }
}

// ---------------------------------------------------------------------------
// causal depthwise conv (K=3) + bias + SiLU -> xc; silu(z) -> sz. float4.
// ---------------------------------------------------------------------------
__global__ __launch_bounds__(256) void conv_silu_k(
    const float* __restrict__ xz, const float* __restrict__ cw,
    const float* __restrict__ cb, float* __restrict__ xc, float* __restrict__ sz) {
  int idx = blockIdx.x * 256 + threadIdx.x;   // float4 unit: (m, d4)
  int m = idx >> 8, d4 = (idx & 255) * 4;
  int t = m & (L - 1);
  const float* base = xz + (size_t)m * (2 * DI);
  float4 r2 = *(const float4*)(base + d4);
  float4 r1 = (t >= 1) ? *(const float4*)(base - 2 * DI + d4) : make_float4(0, 0, 0, 0);
  float4 r0 = (t >= 2) ? *(const float4*)(base - 4 * DI + d4) : make_float4(0, 0, 0, 0);
  float4 zv = *(const float4*)(base + DI + d4);
  float wv[12];
  *(float4*)(wv + 0) = *(const float4*)(cw + d4 * 3 + 0);
  *(float4*)(wv + 4) = *(const float4*)(cw + d4 * 3 + 4);
  *(float4*)(wv + 8) = *(const float4*)(cw + d4 * 3 + 8);
  float4 bv = *(const float4*)(cb + d4);
  float rin0[4] = {r0.x, r0.y, r0.z, r0.w};
  float rin1[4] = {r1.x, r1.y, r1.z, r1.w};
  float rin2[4] = {r2.x, r2.y, r2.z, r2.w};
  float bb[4] = {bv.x, bv.y, bv.z, bv.w};
  float zz[4] = {zv.x, zv.y, zv.z, zv.w};
  float xo[4], zo[4];
#pragma unroll
  for (int j = 0; j < 4; ++j) {
    float v = bb[j];
    v = fmaf(rin0[j], wv[3 * j + 0], v);
    v = fmaf(rin1[j], wv[3 * j + 1], v);
    v = fmaf(rin2[j], wv[3 * j + 2], v);
    xo[j] = v * sigmoidf_(v);
    zo[j] = zz[j] * sigmoidf_(zz[j]);
  }
  *(float4*)(xc + (size_t)idx * 4) = make_float4(xo[0], xo[1], xo[2], xo[3]);
  *(float4*)(sz + (size_t)idx * 4) = make_float4(zo[0], zo[1], zo[2], zo[3]);
}

// ---------------------------------------------------------------------------
// x_proj: (ML,1024) x (97,1024)^T, K split 4 ways, LDS combine, scattered.
// ---------------------------------------------------------------------------
__global__ __launch_bounds__(512) void proj_k(
    const float* __restrict__ xc, const float* __restrict__ xw,
    float* __restrict__ dtp, float* __restrict__ bccf, float* __restrict__ lamv) {
  __shared__ float xs[4][DI];
  __shared__ float pt[3][4][128];
  const int tid = threadIdx.x;
  const int m0 = blockIdx.x * 4;
  const int nn = tid & 127, qq = tid >> 7;
  for (int i = tid; i < 4 * DI; i += 512)
    xs[i >> 10][i & 1023] = xc[(size_t)m0 * DI + i];
  __syncthreads();
  float s0 = 0.f, s1 = 0.f, s2 = 0.f, s3 = 0.f;
  if (nn < PW) {
    const float* wr = xw + (size_t)nn * DI + qq * 256;
    const int kb = qq * 256;
#pragma unroll 4
    for (int k = 0; k < 256; k += 4) {
      float4 w4 = *(const float4*)(wr + k);
      s0 = fmaf(xs[0][kb + k], w4.x, s0); s0 = fmaf(xs[0][kb + k + 1], w4.y, s0);
      s0 = fmaf(xs[0][kb + k + 2], w4.z, s0); s0 = fmaf(xs[0][kb + k + 3], w4.w, s0);
      s1 = fmaf(xs[1][kb + k], w4.x, s1); s1 = fmaf(xs[1][kb + k + 1], w4.y, s1);
      s1 = fmaf(xs[1][kb + k + 2], w4.z, s1); s1 = fmaf(xs[1][kb + k + 3], w4.w, s1);
      s2 = fmaf(xs[2][kb + k], w4.x, s2); s2 = fmaf(xs[2][kb + k + 1], w4.y, s2);
      s2 = fmaf(xs[2][kb + k + 2], w4.z, s2); s2 = fmaf(xs[2][kb + k + 3], w4.w, s2);
      s3 = fmaf(xs[3][kb + k], w4.x, s3); s3 = fmaf(xs[3][kb + k + 1], w4.y, s3);
      s3 = fmaf(xs[3][kb + k + 2], w4.z, s3); s3 = fmaf(xs[3][kb + k + 3], w4.w, s3);
    }
    if (qq > 0) {
      pt[qq - 1][0][nn] = s0; pt[qq - 1][1][nn] = s1;
      pt[qq - 1][2][nn] = s2; pt[qq - 1][3][nn] = s3;
    }
  }
  __syncthreads();
  if (qq == 0 && nn < PW) {
    s0 += pt[0][0][nn] + pt[1][0][nn] + pt[2][0][nn];
    s1 += pt[0][1][nn] + pt[1][1][nn] + pt[2][1][nn];
    s2 += pt[0][2][nn] + pt[1][2][nn] + pt[2][2][nn];
    s3 += pt[0][3][nn] + pt[1][3][nn] + pt[2][3][nn];
    float sv[4] = {s0, s1, s2, s3};
#pragma unroll
    for (int r = 0; r < 4; ++r) {
      int m = m0 + r;
      float s = sv[r];
      if (nn < 32)        dtp[m * 32 + nn] = s;
      else if (nn < 48)   bccf[(m * 16 + nn - 32) * 4 + 0] = s;
      else if (nn < 64)   bccf[(m * 16 + nn - 48) * 4 + 1] = s;
      else if (nn < 80)   bccf[(m * 16 + nn - 64) * 4 + 2] = s;
      else if (nn < 96)   bccf[(m * 16 + nn - 80) * 4 + 3] = s;
      else                lamv[m] = sigmoidf_(s);
    }
  }
}

// ---------------------------------------------------------------------------
// delta = softplus(dtp @ dt_w^T + dt_b); emit packed float4 {dlt, xt, bsc, g}
// ---------------------------------------------------------------------------
__global__ __launch_bounds__(256) void delta_k(
    const float* __restrict__ dtp, const float* __restrict__ dtw,
    const float* __restrict__ dtb, const float* __restrict__ xc,
    const float* __restrict__ lamv, float4* __restrict__ dxbg) {
  __shared__ float ws[256][33];
  __shared__ float ps[8][32];
  const int tid = threadIdx.x;
  const int d0 = blockIdx.x * 256;
  const int m0 = blockIdx.y * 8;
#pragma unroll
  for (int j = 0; j < 8; ++j) {
    int flat = tid * 4 + j * 1024;
    int r = flat >> 5, c = flat & 31;
    float4 v = *(const float4*)(dtw + (size_t)d0 * 32 + flat);
    ws[r][c] = v.x; ws[r][c + 1] = v.y; ws[r][c + 2] = v.z; ws[r][c + 3] = v.w;
  }
  { int i = tid >> 5, r = tid & 31;
    ps[i][r] = dtp[(size_t)(m0 + i) * 32 + r]; }
  __syncthreads();
  float s[8];
  float bias = dtb[d0 + tid];
#pragma unroll
  for (int i = 0; i < 8; ++i) s[i] = bias;
#pragma unroll
  for (int r = 0; r < 32; ++r) {
    float wv = ws[tid][r];
#pragma unroll
    for (int i = 0; i < 8; ++i) s[i] = fmaf(ps[i][r], wv, s[i]);
  }
#pragma unroll
  for (int i = 0; i < 8; ++i) {
    float x = s[i];
    float dlt = (x > 20.f) ? x : log1pf(__expf(x));
    int m = m0 + i;
    float xt = xc[(size_t)m * DI + d0 + tid];
    float lam = lamv[m];
    dxbg[(size_t)m * DI + d0 + tid] = make_float4(dlt, xt, (1.f - lam) * dlt, lam * dlt);
  }
}

// ---------------------------------------------------------------------------
// Chunked selective scan with explicit double-buffered register batches.
// lane = n (0..15); 16 (b,d) channels per block.
// h_t = alpha*(h_{t-1} + bsc*Bx_{t-1}) + g*Bx_t.
// PASS_A: batch 8, B as float2; aggregate via S=sum(dlt).
// PASS_B: batch 4, full float4 {B,C}; DPP 16-lane reduce; ybuf bf16 out.
// ---------------------------------------------------------------------------
template <bool PASS_B>
__global__ __launch_bounds__(256) void scan_pass(
    const float4* __restrict__ dxbg, const float4* __restrict__ bcc,
    const float* __restrict__ sz,
    const float* __restrict__ A_log, const float* __restrict__ A_imag,
    const float* __restrict__ D_skip,
    float2* __restrict__ aggA, float2* __restrict__ aggU,
    unsigned short* __restrict__ ybuf) {
  const int tid = threadIdx.x;
  const int n = tid & 15;
  const int gch = blockIdx.x * 16 + (tid >> 4);
  const int c = blockIdx.y;
  const int b = gch >> 10, d = gch & 1023;
  const int lane = blockIdx.x * 256 + tid;
  const float Ar = -__expf(A_log[d * 16 + n]);
  const float Arl = Ar * 1.44269504f;                  // * log2(e)
  const float Ai = A_imag[d * 16 + n];                 // radians multiplier
  const int t0 = c * CL, mb = b * L;
  const unsigned ix0 = (unsigned)(mb + t0) * DI + d;

  float Bxpr = 0.f, Bxpi = 0.f;
  if (c > 0) {
    float xp = dxbg[ix0 - DI].y;
    float4 bp = bcc[(mb + t0 - 1) * 16 + n];
    Bxpr = bp.x * xp; Bxpi = bp.y * xp;
  }
  float hr = 0.f, hi = 0.f, S = 0.f, Dsk = 0.f;
  if (PASS_B) {
    if (c > 0) {
      float2 h0 = aggU[(c - 1) * NLANES + lane];  // prefix from combine
      hr = h0.x; hi = h0.y;
    }
    Dsk = D_skip[d];
  }

  constexpr int NB = PASS_B ? 4 : 8;     // batch size (steps)
  constexpr int NBAT = CL / NB;          // batches per chunk
  const float4* qp = dxbg + ix0;
  const float4* pp4 = bcc + (size_t)(mb + t0) * 16 + n;
  const float2* pp2 = (const float2*)pp4;   // {Br,Bi} prefix of each float4

  float4 qb[2][NB];
  float4 pb4[2][PASS_B ? NB : 1];
  float2 pb2[2][PASS_B ? 1 : NB];

#define LOADB(bi_, buf_)                                                      \
  {                                                                           \
    _Pragma("unroll")                                                         \
    for (int j = 0; j < NB; ++j) {                                            \
      int t_ = (bi_) * NB + j;                                                \
      qb[buf_][j] = qp[(size_t)t_ * DI];                                      \
      if constexpr (PASS_B) pb4[buf_][j] = pp4[(size_t)t_ * 16];              \
      else                  pb2[buf_][j] = pp2[(size_t)t_ * 32];              \
    }                                                                         \
  }

#define COMPB(bi_, buf_)                                                      \
  {                                                                           \
    _Pragma("unroll")                                                         \
    for (int j = 0; j < NB; ++j) {                                            \
      float4 q = qb[buf_][j];                                                 \
      float Br_, Bi_, Cr_ = 0.f, Ci_ = 0.f;                                   \
      if constexpr (PASS_B) {                                                 \
        float4 pv = pb4[buf_][j]; Br_ = pv.x; Bi_ = pv.y; Cr_ = pv.z; Ci_ = pv.w; \
      } else {                                                                \
        float2 pv = pb2[buf_][j]; Br_ = pv.x; Bi_ = pv.y;                     \
      }                                                                       \
      float ear = EXP2F(q.x * Arl);                                           \
      float sn_, cs_; sincos_poly(q.x * Ai, sn_, cs_);                        \
      float ar = ear * cs_, ai = ear * sn_;                                   \
      float Bxr = Br_ * q.y, Bxi = Bi_ * q.y;                                 \
      float wr_ = fmaf(q.z, Bxpr, hr), wi_ = fmaf(q.z, Bxpi, hi);             \
      hr = fmaf(q.w, Bxr, fmaf(-ai, wi_, ar * wr_));                          \
      hi = fmaf(q.w, Bxi, fmaf(ai, wr_, ar * wi_));                           \
      Bxpr = Bxr; Bxpi = Bxi;                                                 \
      if constexpr (!PASS_B) {                                                \
        S += q.x;                                                             \
      } else {                                                                \
        float yc = fmaf(hi, Ci_, hr * Cr_);                                   \
        yc = dpp_add<0xB1>(yc);                                               \
        yc = dpp_add<0x4E>(yc);                                               \
        yc = dpp_add<0x124>(yc);                                              \
        yc = dpp_add<0x128>(yc);                                              \
        if (n == 0) {                                                         \
          unsigned ixm = ix0 + ((unsigned)((bi_) * NB + j) << 10);            \
          float y = fmaf(Dsk, q.y, yc);                                       \
          ybuf[ixm] = f2bf(y * sz[ixm]);                                      \
        }                                                                     \
      }                                                                       \
    }                                                                         \
  }

  LOADB(0, 0);
#pragma unroll
  for (int bi = 0; bi < NBAT; ++bi) {
    if (bi + 1 < NBAT) LOADB(bi + 1, (bi + 1) & 1);
    COMPB(bi, bi & 1);
  }
#undef LOADB
#undef COMPB

  if (!PASS_B) {
    float earS = EXP2F(S * Arl);
    float rvS = S * Ai * 0.15915494f;     // revolutions for HW sin/cos
    float AaR = earS * COSR(rvS);
    float AaI = earS * SINR(rvS);
    int idx = c * NLANES + lane;
    aggA[idx] = make_float2(AaR, AaI);
    aggU[idx] = make_float2(hr, hi);
  }
}

// in-place prefix: after this, aggU[c] = chunk-(c+1) entry state
__global__ __launch_bounds__(256) void scan_combine_k(
    const float2* __restrict__ aggA, float2* __restrict__ aggU) {
  int gid = blockIdx.x * 256 + threadIdx.x;
  float hr = 0.f, hi = 0.f;
#pragma unroll
  for (int c = 0; c < NCHUNK - 1; ++c) {
    float2 a = aggA[c * NLANES + gid];
    float2 u = aggU[c * NLANES + gid];
    float nr = fmaf(a.x, hr, fmaf(-a.y, hi, u.x));
    float ni = fmaf(a.x, hi, fmaf(a.y, hr, u.y));
    hr = nr; hi = ni;
    aggU[c * NLANES + gid] = make_float2(hr, hi);
  }
}

extern "C" void kernel_launch(void* const* d_in, const int* in_sizes, int n_in,
                              void* d_out, int out_size, void* d_ws, size_t ws_size,
                              hipStream_t stream) {
  const float* x        = (const float*)d_in[0];
  const float* in_proj  = (const float*)d_in[1];
  const float* conv_w   = (const float*)d_in[2];
  const float* conv_b   = (const float*)d_in[3];
  const float* x_proj_w = (const float*)d_in[4];
  const float* dt_w     = (const float*)d_in[5];
  const float* dt_b     = (const float*)d_in[6];
  const float* A_log    = (const float*)d_in[7];
  const float* A_imag   = (const float*)d_in[8];
  const float* D_skip   = (const float*)d_in[9];
  const float* out_proj = (const float*)d_in[10];
  float* out = (float*)d_out;

  float* ws = (float*)d_ws;
  float*  xz    = ws; ws += (size_t)ML * 2 * DI;                 // 16.8 MB
  float*  xc    = ws; ws += (size_t)ML * DI;                     //  8.4 MB
  float*  sz    = ws; ws += (size_t)ML * DI;                     //  8.4 MB
  float4* dxbg  = (float4*)ws; ws += (size_t)(ML + 1) * DI * 4;  // 33.6 MB
  float*  dtp   = ws; ws += (size_t)ML * 32;
  float*  bccf  = ws; ws += (size_t)(ML + 1) * 16 * 4;
  float*  lamv  = ws; ws += ML;
  float2* aggA  = (float2*)ws; ws += (size_t)NCHUNK * NLANES * 2; // 8.4 MB
  float2* aggU  = (float2*)ws; ws += (size_t)NCHUNK * NLANES * 2; // 8.4 MB
  unsigned short* xb   = (unsigned short*)ws; ws += (size_t)ML * DM / 2;
  unsigned short* wb1  = (unsigned short*)ws; ws += (size_t)(2 * DI) * DM / 2;
  unsigned short* wb2  = (unsigned short*)ws; ws += (size_t)DM * DI / 2;
  unsigned short* ybuf = (unsigned short*)ws; ws += (size_t)ML * DI / 2;

  const int n0 = ML * DM / 4, n1 = 2 * DI * DM / 4, n2 = DM * DI / 4;
  cvt3_k<<<(n0 + n1 + n2 + 255) / 256, 256, 0, stream>>>(x, xb, n0, in_proj, wb1, n1,
                                                         out_proj, wb2, n2);
  gemm_bf16_64<<<dim3(2 * DI / 64, ML / 64), 256, 0, stream>>>(
      (const short*)xb, (const short*)wb1, xz, ML, 2 * DI, DM);
  conv_silu_k<<<ML * DI / 4 / 256, 256, 0, stream>>>(xz, conv_w, conv_b, xc, sz);
  proj_k<<<ML / 4, 512, 0, stream>>>(xc, x_proj_w, dtp, bccf, lamv);
  delta_k<<<dim3(DI / 256, ML / 8), 256, 0, stream>>>(dtp, dt_w, dt_b, xc, lamv, dxbg);
  scan_pass<false><<<dim3(128, NCHUNK - 1), 256, 0, stream>>>(
      dxbg, (const float4*)bccf, sz, A_log, A_imag, D_skip, aggA, aggU, nullptr);
  scan_combine_k<<<NLANES / 256, 256, 0, stream>>>(aggA, aggU);
  scan_pass<true><<<dim3(128, NCHUNK), 256, 0, stream>>>(
      dxbg, (const float4*)bccf, sz, A_log, A_imag, D_skip, aggA, aggU, ybuf);
  gemm_bf16_64<<<dim3(DM / 64, ML / 64), 256, 0, stream>>>(
      (const short*)ybuf, (const short*)wb2, out, ML, DM, DI);
}

// Round 8
// 175.062 us; speedup vs baseline: 1.1970x; 1.1970x over previous
//
#include <hip/hip_runtime.h>

// Mamba block forward. Round 8: LDS-staged scan (zero global loads in the
// recurrence loop), dx shrunk to float2, B/C split into float2 arrays.
constexpr int B  = 2, L = 1024, DM = 512, DI = 1024, NST = 16, PW = 97;
constexpr int ML = B * L;                   // 2048 rows
constexpr int NCHUNK = 32, CL = L / NCHUNK; // 32 chunks x 32 steps
constexpr int NLANES = B * DI * NST;        // 32768 scan lanes

#define DEV_INLINE __device__ __forceinline__

typedef __attribute__((ext_vector_type(8))) short bf16x8;   // 8 bf16 (4 VGPRs)
typedef __attribute__((ext_vector_type(4))) float f32x4;    // 4 fp32 acc

DEV_INLINE float sigmoidf_(float x) { return 1.f / (1.f + __expf(-x)); }
DEV_INLINE unsigned short f2bf(float f) {
  unsigned int u = __float_as_uint(f);
  return (unsigned short)((u + 0x7FFFu + ((u >> 16) & 1u)) >> 16);  // RNE
}

#if __has_builtin(__builtin_amdgcn_exp2f)
#define EXP2F(x) __builtin_amdgcn_exp2f(x)
#else
#define EXP2F(x) exp2f(x)
#endif
#if __has_builtin(__builtin_amdgcn_sinf)
#define SINR(x) __builtin_amdgcn_sinf(x)   // sin(2*pi*x), x in revolutions
#define COSR(x) __builtin_amdgcn_cosf(x)
#else
#define SINR(x) __sinf((x) * 6.2831853f)
#define COSR(x) __cosf((x) * 6.2831853f)
#endif

// Taylor sin/cos (radians), valid |th| <~ 2 with <5e-5 error. Shares t2.
DEV_INLINE void sincos_poly(float th, float& s, float& c) {
  float t2 = th * th;
  float u = fmaf(t2, 2.7557319e-6f, -1.9841270e-4f);
  u = fmaf(t2, u, 8.3333333e-3f);
  u = fmaf(t2, u, -0.16666667f);
  u = fmaf(t2, u, 1.f);
  s = th * u;
  float v = fmaf(t2, 2.4801587e-5f, -1.3888889e-3f);
  v = fmaf(t2, v, 4.1666667e-2f);
  v = fmaf(t2, v, -0.5f);
  c = fmaf(t2, v, 1.f);
}

// DPP 16-lane add-reduce (quad_perm xor1, xor2, row_ror:4, row_ror:8)
template <int CTRL>
DEV_INLINE float dpp_add(float v) {
  int x = __builtin_amdgcn_update_dpp(0, __float_as_int(v), CTRL, 0xF, 0xF, true);
  return v + __int_as_float(x);
}

// ---------------------------------------------------------------------------
// f32 -> bf16 convert, 3 segments in one launch (x, in_proj_w, out_proj_w)
// ---------------------------------------------------------------------------
__global__ __launch_bounds__(256) void cvt3_k(
    const float* __restrict__ i0, unsigned short* __restrict__ o0, int n0,
    const float* __restrict__ i1, unsigned short* __restrict__ o1, int n1,
    const float* __restrict__ i2, unsigned short* __restrict__ o2, int n2) {
  int i = blockIdx.x * 256 + threadIdx.x;   // in float4 units
  const float* in; unsigned short* out; int off;
  if (i < n0)              { in = i0; out = o0; off = i; }
  else if (i < n0 + n1)    { in = i1; out = o1; off = i - n0; }
  else if (i < n0 + n1 + n2) { in = i2; out = o2; off = i - n0 - n1; }
  else return;
  float4 v = ((const float4*)in)[off];
  ((ushort4*)out)[off] = make_ushort4(f2bf(v.x), f2bf(v.y), f2bf(v.z), f2bf(v.w));
}

// ---------------------------------------------------------------------------
// bf16 MFMA GEMM, 64x64 tile, BK=64, 4 waves, XOR-swizzled LDS.
// ---------------------------------------------------------------------------
DEV_INLINE int swz(int row, int kb) { return (row << 7) + (kb ^ ((row & 7) << 4)); }

__global__ __launch_bounds__(256) void gemm_bf16_64(
    const short* __restrict__ A, const short* __restrict__ W,
    float* __restrict__ C, int M, int N, int K) {
  __shared__ char ldsb[16384];               // A [0,8K), W [8K,16K)
  const int tid = threadIdx.x;
  const int lane = tid & 63, wv = tid >> 6;
  const int bm = blockIdx.y * 64, bn = blockIdx.x * 64;

  f32x4 acc[4];
#pragma unroll
  for (int nb = 0; nb < 4; ++nb) acc[nb] = (f32x4){0.f, 0.f, 0.f, 0.f};

  for (int k0 = 0; k0 < K; k0 += 64) {
#pragma unroll
    for (int i = 0; i < 2; ++i) {
      int off = i * 4096 + tid * 16;
      int row = off >> 7, kb = off & 127;
      bf16x8 va = *(const bf16x8*)(A + (size_t)(bm + row) * K + k0 + (kb >> 1));
      bf16x8 vw = *(const bf16x8*)(W + (size_t)(bn + row) * K + k0 + (kb >> 1));
      *(bf16x8*)(ldsb + swz(row, kb)) = va;
      *(bf16x8*)(ldsb + 8192 + swz(row, kb)) = vw;
    }
    __syncthreads();
#pragma unroll
    for (int ks = 0; ks < 2; ++ks) {
      const int kb = ks * 64 + ((lane >> 4) << 4);
      bf16x8 af = *(const bf16x8*)(ldsb + swz(wv * 16 + (lane & 15), kb));
#pragma unroll
      for (int nb = 0; nb < 4; ++nb) {
        bf16x8 bfv = *(const bf16x8*)(ldsb + 8192 + swz(nb * 16 + (lane & 15), kb));
        acc[nb] = __builtin_amdgcn_mfma_f32_16x16x32_bf16(af, bfv, acc[nb], 0, 0, 0);
      }
    }
    __syncthreads();
  }
#pragma unroll
  for (int nb = 0; nb < 4; ++nb) {
    int col = bn + nb * 16 + (lane & 15);
    int row0 = bm + wv * 16 + ((lane >> 4) << 2);
#pragma unroll
    for (int j = 0; j < 4; ++j)
      C[(size_t)(row0 + j) * N + col] = acc[nb][j];
  }
}

// ---------------------------------------------------------------------------
// causal depthwise conv (K=3) + bias + SiLU -> xc; silu(z) -> sz. float4.
// ---------------------------------------------------------------------------
__global__ __launch_bounds__(256) void conv_silu_k(
    const float* __restrict__ xz, const float* __restrict__ cw,
    const float* __restrict__ cb, float* __restrict__ xc, float* __restrict__ sz) {
  int idx = blockIdx.x * 256 + threadIdx.x;   // float4 unit: (m, d4)
  int m = idx >> 8, d4 = (idx & 255) * 4;
  int t = m & (L - 1);
  const float* base = xz + (size_t)m * (2 * DI);
  float4 r2 = *(const float4*)(base + d4);
  float4 r1 = (t >= 1) ? *(const float4*)(base - 2 * DI + d4) : make_float4(0, 0, 0, 0);
  float4 r0 = (t >= 2) ? *(const float4*)(base - 4 * DI + d4) : make_float4(0, 0, 0, 0);
  float4 zv = *(const float4*)(base + DI + d4);
  float wv[12];
  *(float4*)(wv + 0) = *(const float4*)(cw + d4 * 3 + 0);
  *(float4*)(wv + 4) = *(const float4*)(cw + d4 * 3 + 4);
  *(float4*)(wv + 8) = *(const float4*)(cw + d4 * 3 + 8);
  float4 bv = *(const float4*)(cb + d4);
  float rin0[4] = {r0.x, r0.y, r0.z, r0.w};
  float rin1[4] = {r1.x, r1.y, r1.z, r1.w};
  float rin2[4] = {r2.x, r2.y, r2.z, r2.w};
  float bb[4] = {bv.x, bv.y, bv.z, bv.w};
  float zz[4] = {zv.x, zv.y, zv.z, zv.w};
  float xo[4], zo[4];
#pragma unroll
  for (int j = 0; j < 4; ++j) {
    float v = bb[j];
    v = fmaf(rin0[j], wv[3 * j + 0], v);
    v = fmaf(rin1[j], wv[3 * j + 1], v);
    v = fmaf(rin2[j], wv[3 * j + 2], v);
    xo[j] = v * sigmoidf_(v);
    zo[j] = zz[j] * sigmoidf_(zz[j]);
  }
  *(float4*)(xc + (size_t)idx * 4) = make_float4(xo[0], xo[1], xo[2], xo[3]);
  *(float4*)(sz + (size_t)idx * 4) = make_float4(zo[0], zo[1], zo[2], zo[3]);
}

// ---------------------------------------------------------------------------
// x_proj: (ML,1024) x (97,1024)^T, K split 4 ways, LDS combine.
// Outputs: dtp[m*32+r], bc2f[(m*16+n)*2+{0,1}]={Br,Bi},
//          cc2f likewise {Cr,Ci}, lamv[m]=sigmoid(lam).
// ---------------------------------------------------------------------------
__global__ __launch_bounds__(512) void proj_k(
    const float* __restrict__ xc, const float* __restrict__ xw,
    float* __restrict__ dtp, float* __restrict__ bc2f,
    float* __restrict__ cc2f, float* __restrict__ lamv) {
  __shared__ float xs[4][DI];
  __shared__ float pt[3][4][128];
  const int tid = threadIdx.x;
  const int m0 = blockIdx.x * 4;
  const int nn = tid & 127, qq = tid >> 7;
  for (int i = tid; i < 4 * DI; i += 512)
    xs[i >> 10][i & 1023] = xc[(size_t)m0 * DI + i];
  __syncthreads();
  float s0 = 0.f, s1 = 0.f, s2 = 0.f, s3 = 0.f;
  if (nn < PW) {
    const float* wr = xw + (size_t)nn * DI + qq * 256;
    const int kb = qq * 256;
#pragma unroll 4
    for (int k = 0; k < 256; k += 4) {
      float4 w4 = *(const float4*)(wr + k);
      s0 = fmaf(xs[0][kb + k], w4.x, s0); s0 = fmaf(xs[0][kb + k + 1], w4.y, s0);
      s0 = fmaf(xs[0][kb + k + 2], w4.z, s0); s0 = fmaf(xs[0][kb + k + 3], w4.w, s0);
      s1 = fmaf(xs[1][kb + k], w4.x, s1); s1 = fmaf(xs[1][kb + k + 1], w4.y, s1);
      s1 = fmaf(xs[1][kb + k + 2], w4.z, s1); s1 = fmaf(xs[1][kb + k + 3], w4.w, s1);
      s2 = fmaf(xs[2][kb + k], w4.x, s2); s2 = fmaf(xs[2][kb + k + 1], w4.y, s2);
      s2 = fmaf(xs[2][kb + k + 2], w4.z, s2); s2 = fmaf(xs[2][kb + k + 3], w4.w, s2);
      s3 = fmaf(xs[3][kb + k], w4.x, s3); s3 = fmaf(xs[3][kb + k + 1], w4.y, s3);
      s3 = fmaf(xs[3][kb + k + 2], w4.z, s3); s3 = fmaf(xs[3][kb + k + 3], w4.w, s3);
    }
    if (qq > 0) {
      pt[qq - 1][0][nn] = s0; pt[qq - 1][1][nn] = s1;
      pt[qq - 1][2][nn] = s2; pt[qq - 1][3][nn] = s3;
    }
  }
  __syncthreads();
  if (qq == 0 && nn < PW) {
    s0 += pt[0][0][nn] + pt[1][0][nn] + pt[2][0][nn];
    s1 += pt[0][1][nn] + pt[1][1][nn] + pt[2][1][nn];
    s2 += pt[0][2][nn] + pt[1][2][nn] + pt[2][2][nn];
    s3 += pt[0][3][nn] + pt[1][3][nn] + pt[2][3][nn];
    float sv[4] = {s0, s1, s2, s3};
#pragma unroll
    for (int r = 0; r < 4; ++r) {
      int m = m0 + r;
      float s = sv[r];
      if (nn < 32)        dtp[m * 32 + nn] = s;
      else if (nn < 48)   bc2f[(m * 16 + nn - 32) * 2 + 0] = s;
      else if (nn < 64)   bc2f[(m * 16 + nn - 48) * 2 + 1] = s;
      else if (nn < 80)   cc2f[(m * 16 + nn - 64) * 2 + 0] = s;
      else if (nn < 96)   cc2f[(m * 16 + nn - 80) * 2 + 1] = s;
      else                lamv[m] = sigmoidf_(s);
    }
  }
}

// ---------------------------------------------------------------------------
// delta = softplus(dtp @ dt_w^T + dt_b); emit packed float2 {dlt, xt}
// ---------------------------------------------------------------------------
__global__ __launch_bounds__(256) void delta_k(
    const float* __restrict__ dtp, const float* __restrict__ dtw,
    const float* __restrict__ dtb, const float* __restrict__ xc,
    float2* __restrict__ dx2) {
  __shared__ float ws[256][33];
  __shared__ float ps[8][32];
  const int tid = threadIdx.x;
  const int d0 = blockIdx.x * 256;
  const int m0 = blockIdx.y * 8;
#pragma unroll
  for (int j = 0; j < 8; ++j) {
    int flat = tid * 4 + j * 1024;
    int r = flat >> 5, c = flat & 31;
    float4 v = *(const float4*)(dtw + (size_t)d0 * 32 + flat);
    ws[r][c] = v.x; ws[r][c + 1] = v.y; ws[r][c + 2] = v.z; ws[r][c + 3] = v.w;
  }
  { int i = tid >> 5, r = tid & 31;
    ps[i][r] = dtp[(size_t)(m0 + i) * 32 + r]; }
  __syncthreads();
  float s[8];
  float bias = dtb[d0 + tid];
#pragma unroll
  for (int i = 0; i < 8; ++i) s[i] = bias;
#pragma unroll
  for (int r = 0; r < 32; ++r) {
    float wv = ws[tid][r];
#pragma unroll
    for (int i = 0; i < 8; ++i) s[i] = fmaf(ps[i][r], wv, s[i]);
  }
#pragma unroll
  for (int i = 0; i < 8; ++i) {
    float x = s[i];
    float dlt = (x > 20.f) ? x : log1pf(__expf(x));
    int m = m0 + i;
    float xt = xc[(size_t)m * DI + d0 + tid];
    dx2[(size_t)m * DI + d0 + tid] = make_float2(dlt, xt);
  }
}

// ---------------------------------------------------------------------------
// LDS-staged chunked scan. Block = 16 channels x 16 n = 256 thr, one chunk.
// Stage {dlt,xt,bsc,g} (8KB) + B (4KB) [+ C (4KB) pass B] into LDS once,
// then CL steps of pure LDS+VALU. No global loads in the recurrence loop.
// ---------------------------------------------------------------------------
template <bool PASS_B>
__global__ __launch_bounds__(256, 8) void scan_pass(
    const float2* __restrict__ dx2, const float* __restrict__ lamv,
    const float2* __restrict__ bc2, const float2* __restrict__ cc2,
    const float* __restrict__ sz,
    const float* __restrict__ A_log, const float* __restrict__ A_imag,
    const float* __restrict__ D_skip,
    float2* __restrict__ aggA, float2* __restrict__ aggU,
    unsigned short* __restrict__ ybuf) {
  __shared__ float4 qx[CL][16];                  // {dlt, xt, bsc, g} per (t,ch)
  __shared__ float2 bcl[CL][16];                 // {Br, Bi} per (t,n)
  __shared__ float2 ccl[PASS_B ? CL : 1][16];    // {Cr, Ci} per (t,n)

  const int tid = threadIdx.x;
  const int n = tid & 15, ch = tid >> 4;
  const int bx = blockIdx.x, c = blockIdx.y;
  const int b = bx >> 6, d0 = (bx & 63) * 16;
  const int d = d0 + ch;
  const int lane = bx * 256 + tid;
  const int t0 = c * CL, mb = b * L;

  // ---- stage chunk into LDS ----
  {
    int t = tid >> 3, pr = tid & 7;              // 32 t x 8 channel-pairs
    size_t gi = (size_t)(mb + t0 + t) * DI + d0 + pr * 2;
    float4 v = *(const float4*)(dx2 + gi);       // {dlt0,xt0,dlt1,xt1}
    float lamt = lamv[mb + t0 + t];
    float g0 = lamt * v.x, g1 = lamt * v.z;
    qx[t][pr * 2 + 0] = make_float4(v.x, v.y, v.x - g0, g0);
    qx[t][pr * 2 + 1] = make_float4(v.z, v.w, v.z - g1, g1);
    size_t bi = (size_t)(mb + t0 + t) * 16 + pr * 2;
    float4 bv = *(const float4*)(bc2 + bi);      // two float2 B entries
    bcl[t][pr * 2 + 0] = make_float2(bv.x, bv.y);
    bcl[t][pr * 2 + 1] = make_float2(bv.z, bv.w);
    if constexpr (PASS_B) {
      float4 cv = *(const float4*)(cc2 + bi);
      ccl[t][pr * 2 + 0] = make_float2(cv.x, cv.y);
      ccl[t][pr * 2 + 1] = make_float2(cv.z, cv.w);
    }
  }

  const float Ar = -__expf(A_log[d * 16 + n]);
  const float Arl = Ar * 1.44269504f;                  // * log2(e)
  const float Ai = A_imag[d * 16 + n];

  float Bxpr = 0.f, Bxpi = 0.f;
  if (c > 0) {
    float xp = dx2[(size_t)(mb + t0 - 1) * DI + d].y;
    float2 bp = bc2[(size_t)(mb + t0 - 1) * 16 + n];
    Bxpr = bp.x * xp; Bxpi = bp.y * xp;
  }
  float hr = 0.f, hi = 0.f, S = 0.f, Dsk = 0.f;
  if (PASS_B) {
    if (c > 0) {
      float2 h0 = aggU[(c - 1) * NLANES + lane];  // prefix from combine
      hr = h0.x; hi = h0.y;
    }
    Dsk = D_skip[d];
  }
  const unsigned ix0 = (unsigned)(mb + t0) * DI + d;

  __syncthreads();

  // ---- recurrence: pure LDS + VALU ----
#pragma unroll
  for (int t = 0; t < CL; ++t) {
    float4 q = qx[t][ch];                 // ds_read_b128, 4 addrs/wave
    float2 bv = bcl[t][n];                // ds_read_b64, 16 addrs bcast x4
    float ear = EXP2F(q.x * Arl);
    float sn, cs; sincos_poly(q.x * Ai, sn, cs);
    float ar = ear * cs, ai = ear * sn;
    float Bxr = bv.x * q.y, Bxi = bv.y * q.y;
    float wr = fmaf(q.z, Bxpr, hr), wi = fmaf(q.z, Bxpi, hi);
    hr = fmaf(q.w, Bxr, fmaf(-ai, wi, ar * wr));
    hi = fmaf(q.w, Bxi, fmaf(ai, wr, ar * wi));
    Bxpr = Bxr; Bxpi = Bxi;
    if constexpr (!PASS_B) {
      S += q.x;
    } else {
      float2 cv = ccl[t][n];
      float yc = fmaf(hi, cv.y, hr * cv.x);   // Re(h * conj(C))
      yc = dpp_add<0xB1>(yc);
      yc = dpp_add<0x4E>(yc);
      yc = dpp_add<0x124>(yc);
      yc = dpp_add<0x128>(yc);
      if (n == 0) {
        unsigned ixm = ix0 + ((unsigned)t << 10);
        float y = fmaf(Dsk, q.y, yc);
        ybuf[ixm] = f2bf(y * sz[ixm]);
      }
    }
  }
  if (!PASS_B) {
    float earS = EXP2F(S * Arl);
    float rvS = S * Ai * 0.15915494f;     // revolutions for HW sin/cos
    float AaR = earS * COSR(rvS);
    float AaI = earS * SINR(rvS);
    int idx = c * NLANES + lane;
    aggA[idx] = make_float2(AaR, AaI);
    aggU[idx] = make_float2(hr, hi);
  }
}

// in-place prefix: after this, aggU[c] = chunk-(c+1) entry state
__global__ __launch_bounds__(256) void scan_combine_k(
    const float2* __restrict__ aggA, float2* __restrict__ aggU) {
  int gid = blockIdx.x * 256 + threadIdx.x;
  float hr = 0.f, hi = 0.f;
#pragma unroll
  for (int c = 0; c < NCHUNK - 1; ++c) {
    float2 a = aggA[c * NLANES + gid];
    float2 u = aggU[c * NLANES + gid];
    float nr = fmaf(a.x, hr, fmaf(-a.y, hi, u.x));
    float ni = fmaf(a.x, hi, fmaf(a.y, hr, u.y));
    hr = nr; hi = ni;
    aggU[c * NLANES + gid] = make_float2(hr, hi);
  }
}

extern "C" void kernel_launch(void* const* d_in, const int* in_sizes, int n_in,
                              void* d_out, int out_size, void* d_ws, size_t ws_size,
                              hipStream_t stream) {
  const float* x        = (const float*)d_in[0];
  const float* in_proj  = (const float*)d_in[1];
  const float* conv_w   = (const float*)d_in[2];
  const float* conv_b   = (const float*)d_in[3];
  const float* x_proj_w = (const float*)d_in[4];
  const float* dt_w     = (const float*)d_in[5];
  const float* dt_b     = (const float*)d_in[6];
  const float* A_log    = (const float*)d_in[7];
  const float* A_imag   = (const float*)d_in[8];
  const float* D_skip   = (const float*)d_in[9];
  const float* out_proj = (const float*)d_in[10];
  float* out = (float*)d_out;

  float* ws = (float*)d_ws;
  float*  xz    = ws; ws += (size_t)ML * 2 * DI;                 // 16.8 MB
  float*  xc    = ws; ws += (size_t)ML * DI;                     //  8.4 MB
  float*  sz    = ws; ws += (size_t)ML * DI;                     //  8.4 MB
  float2* dx2   = (float2*)ws; ws += (size_t)ML * DI * 2;        // 16.8 MB
  float*  dtp   = ws; ws += (size_t)ML * 32;
  float*  bc2f  = ws; ws += (size_t)ML * 32;                     // float2[ML*16]
  float*  cc2f  = ws; ws += (size_t)ML * 32;
  float*  lamv  = ws; ws += ML;
  float2* aggA  = (float2*)ws; ws += (size_t)NCHUNK * NLANES * 2; // 8.4 MB
  float2* aggU  = (float2*)ws; ws += (size_t)NCHUNK * NLANES * 2; // 8.4 MB
  unsigned short* xb   = (unsigned short*)ws; ws += (size_t)ML * DM / 2;
  unsigned short* wb1  = (unsigned short*)ws; ws += (size_t)(2 * DI) * DM / 2;
  unsigned short* wb2  = (unsigned short*)ws; ws += (size_t)DM * DI / 2;
  unsigned short* ybuf = (unsigned short*)ws; ws += (size_t)ML * DI / 2;

  const int n0 = ML * DM / 4, n1 = 2 * DI * DM / 4, n2 = DM * DI / 4;
  cvt3_k<<<(n0 + n1 + n2 + 255) / 256, 256, 0, stream>>>(x, xb, n0, in_proj, wb1, n1,
                                                         out_proj, wb2, n2);
  gemm_bf16_64<<<dim3(2 * DI / 64, ML / 64), 256, 0, stream>>>(
      (const short*)xb, (const short*)wb1, xz, ML, 2 * DI, DM);
  conv_silu_k<<<ML * DI / 4 / 256, 256, 0, stream>>>(xz, conv_w, conv_b, xc, sz);
  proj_k<<<ML / 4, 512, 0, stream>>>(xc, x_proj_w, dtp, bc2f, cc2f, lamv);
  delta_k<<<dim3(DI / 256, ML / 8), 256, 0, stream>>>(dtp, dt_w, dt_b, xc, dx2);
  scan_pass<false><<<dim3(128, NCHUNK - 1), 256, 0, stream>>>(
      dx2, lamv, (const float2*)bc2f, (const float2*)cc2f, sz,
      A_log, A_imag, D_skip, aggA, aggU, nullptr);
  scan_combine_k<<<NLANES / 256, 256, 0, stream>>>(aggA, aggU);
  scan_pass<true><<<dim3(128, NCHUNK), 256, 0, stream>>>(
      dx2, lamv, (const float2*)bc2f, (const float2*)cc2f, sz,
      A_log, A_imag, D_skip, aggA, aggU, ybuf);
  gemm_bf16_64<<<dim3(DM / 64, ML / 64), 256, 0, stream>>>(
      (const short*)ybuf, (const short*)wb2, out, ML, DM, DI);
}

// Round 9
// 141.180 us; speedup vs baseline: 1.4843x; 1.2400x over previous
//
#include <hip/hip_runtime.h>

// Mamba block forward. Round 9: padded scan LDS (kill write conflicts),
// pass-B LDS y-epilogue, proj+delta fusion, gemm2 split-K.
constexpr int B  = 2, L = 1024, DM = 512, DI = 1024, NST = 16, PW = 97;
constexpr int ML = B * L;                   // 2048 rows
constexpr int NCHUNK = 32, CL = L / NCHUNK; // 32 chunks x 32 steps
constexpr int NLANES = B * DI * NST;        // 32768 scan lanes

#define DEV_INLINE __device__ __forceinline__

typedef __attribute__((ext_vector_type(8))) short bf16x8;   // 8 bf16 (4 VGPRs)
typedef __attribute__((ext_vector_type(4))) float f32x4;    // 4 fp32 acc

DEV_INLINE float sigmoidf_(float x) { return 1.f / (1.f + __expf(-x)); }
DEV_INLINE unsigned short f2bf(float f) {
  unsigned int u = __float_as_uint(f);
  return (unsigned short)((u + 0x7FFFu + ((u >> 16) & 1u)) >> 16);  // RNE
}

#if __has_builtin(__builtin_amdgcn_exp2f)
#define EXP2F(x) __builtin_amdgcn_exp2f(x)
#else
#define EXP2F(x) exp2f(x)
#endif
#if __has_builtin(__builtin_amdgcn_sinf)
#define SINR(x) __builtin_amdgcn_sinf(x)   // sin(2*pi*x), x in revolutions
#define COSR(x) __builtin_amdgcn_cosf(x)
#else
#define SINR(x) __sinf((x) * 6.2831853f)
#define COSR(x) __cosf((x) * 6.2831853f)
#endif

// Taylor sin/cos order 7/6 (radians), |th| <= ~1, err < 3e-5. Shares t2.
DEV_INLINE void sincos_poly(float th, float& s, float& c) {
  float t2 = th * th;
  float u = fmaf(t2, -1.9841270e-4f, 8.3333333e-3f);
  u = fmaf(t2, u, -0.16666667f);
  u = fmaf(t2, u, 1.f);
  s = th * u;
  float v = fmaf(t2, -1.3888889e-3f, 4.1666667e-2f);
  v = fmaf(t2, v, -0.5f);
  c = fmaf(t2, v, 1.f);
}

// DPP 16-lane add-reduce (quad_perm xor1, xor2, row_ror:4, row_ror:8)
template <int CTRL>
DEV_INLINE float dpp_add(float v) {
  int x = __builtin_amdgcn_update_dpp(0, __float_as_int(v), CTRL, 0xF, 0xF, true);
  return v + __int_as_float(x);
}

// ---------------------------------------------------------------------------
// f32 -> bf16 convert, 3 segments in one launch (x, in_proj_w, out_proj_w)
// ---------------------------------------------------------------------------
__global__ __launch_bounds__(256) void cvt3_k(
    const float* __restrict__ i0, unsigned short* __restrict__ o0, int n0,
    const float* __restrict__ i1, unsigned short* __restrict__ o1, int n1,
    const float* __restrict__ i2, unsigned short* __restrict__ o2, int n2) {
  int i = blockIdx.x * 256 + threadIdx.x;   // in float4 units
  const float* in; unsigned short* out; int off;
  if (i < n0)              { in = i0; out = o0; off = i; }
  else if (i < n0 + n1)    { in = i1; out = o1; off = i - n0; }
  else if (i < n0 + n1 + n2) { in = i2; out = o2; off = i - n0 - n1; }
  else return;
  float4 v = ((const float4*)in)[off];
  ((ushort4*)out)[off] = make_ushort4(f2bf(v.x), f2bf(v.y), f2bf(v.z), f2bf(v.w));
}

// ---------------------------------------------------------------------------
// bf16 MFMA GEMM, 64x64 tile, BK=64, 4 waves, XOR-swizzled LDS.
// ---------------------------------------------------------------------------
DEV_INLINE int swz(int row, int kb) { return (row << 7) + (kb ^ ((row & 7) << 4)); }

__global__ __launch_bounds__(256) void gemm_bf16_64(
    const short* __restrict__ A, const short* __restrict__ W,
    float* __restrict__ C, int M, int N, int K) {
  __shared__ char ldsb[16384];               // A [0,8K), W [8K,16K)
  const int tid = threadIdx.x;
  const int lane = tid & 63, wv = tid >> 6;
  const int bm = blockIdx.y * 64, bn = blockIdx.x * 64;

  f32x4 acc[4];
#pragma unroll
  for (int nb = 0; nb < 4; ++nb) acc[nb] = (f32x4){0.f, 0.f, 0.f, 0.f};

  for (int k0 = 0; k0 < K; k0 += 64) {
#pragma unroll
    for (int i = 0; i < 2; ++i) {
      int off = i * 4096 + tid * 16;
      int row = off >> 7, kb = off & 127;
      bf16x8 va = *(const bf16x8*)(A + (size_t)(bm + row) * K + k0 + (kb >> 1));
      bf16x8 vw = *(const bf16x8*)(W + (size_t)(bn + row) * K + k0 + (kb >> 1));
      *(bf16x8*)(ldsb + swz(row, kb)) = va;
      *(bf16x8*)(ldsb + 8192 + swz(row, kb)) = vw;
    }
    __syncthreads();
#pragma unroll
    for (int ks = 0; ks < 2; ++ks) {
      const int kb = ks * 64 + ((lane >> 4) << 4);
      bf16x8 af = *(const bf16x8*)(ldsb + swz(wv * 16 + (lane & 15), kb));
#pragma unroll
      for (int nb = 0; nb < 4; ++nb) {
        bf16x8 bfv = *(const bf16x8*)(ldsb + 8192 + swz(nb * 16 + (lane & 15), kb));
        acc[nb] = __builtin_amdgcn_mfma_f32_16x16x32_bf16(af, bfv, acc[nb], 0, 0, 0);
      }
    }
    __syncthreads();
  }
#pragma unroll
  for (int nb = 0; nb < 4; ++nb) {
    int col = bn + nb * 16 + (lane & 15);
    int row0 = bm + wv * 16 + ((lane >> 4) << 2);
#pragma unroll
    for (int j = 0; j < 4; ++j)
      C[(size_t)(row0 + j) * N + col] = acc[nb][j];
  }
}

// Same GEMM, split-K: blockIdx.z selects a 256-wide K slice, writes partials.
__global__ __launch_bounds__(256) void gemm_bf16_64_sk(
    const short* __restrict__ A, const short* __restrict__ W,
    float* __restrict__ P, int M, int N, int K) {
  __shared__ char ldsb[16384];
  const int tid = threadIdx.x;
  const int lane = tid & 63, wv = tid >> 6;
  const int bm = blockIdx.y * 64, bn = blockIdx.x * 64;
  const int kz = blockIdx.z * 256;
  float* Cp = P + (size_t)blockIdx.z * M * N;

  f32x4 acc[4];
#pragma unroll
  for (int nb = 0; nb < 4; ++nb) acc[nb] = (f32x4){0.f, 0.f, 0.f, 0.f};

  for (int k0 = kz; k0 < kz + 256; k0 += 64) {
#pragma unroll
    for (int i = 0; i < 2; ++i) {
      int off = i * 4096 + tid * 16;
      int row = off >> 7, kb = off & 127;
      bf16x8 va = *(const bf16x8*)(A + (size_t)(bm + row) * K + k0 + (kb >> 1));
      bf16x8 vw = *(const bf16x8*)(W + (size_t)(bn + row) * K + k0 + (kb >> 1));
      *(bf16x8*)(ldsb + swz(row, kb)) = va;
      *(bf16x8*)(ldsb + 8192 + swz(row, kb)) = vw;
    }
    __syncthreads();
#pragma unroll
    for (int ks = 0; ks < 2; ++ks) {
      const int kb = ks * 64 + ((lane >> 4) << 4);
      bf16x8 af = *(const bf16x8*)(ldsb + swz(wv * 16 + (lane & 15), kb));
#pragma unroll
      for (int nb = 0; nb < 4; ++nb) {
        bf16x8 bfv = *(const bf16x8*)(ldsb + 8192 + swz(nb * 16 + (lane & 15), kb));
        acc[nb] = __builtin_amdgcn_mfma_f32_16x16x32_bf16(af, bfv, acc[nb], 0, 0, 0);
      }
    }
    __syncthreads();
  }
#pragma unroll
  for (int nb = 0; nb < 4; ++nb) {
    int col = bn + nb * 16 + (lane & 15);
    int row0 = bm + wv * 16 + ((lane >> 4) << 2);
#pragma unroll
    for (int j = 0; j < 4; ++j)
      Cp[(size_t)(row0 + j) * N + col] = acc[nb][j];
  }
}

// out = sum of 4 K-slice partials (float4 vectorized)
__global__ __launch_bounds__(256) void addp4_k(
    const float4* __restrict__ p, float4* __restrict__ out) {
  constexpr int NN = ML * DM / 4;
  int i = blockIdx.x * 256 + threadIdx.x;
  float4 a = p[i], b = p[i + NN], c = p[i + 2 * NN], d = p[i + 3 * NN];
  out[i] = make_float4(a.x + b.x + c.x + d.x, a.y + b.y + c.y + d.y,
                       a.z + b.z + c.z + d.z, a.w + b.w + c.w + d.w);
}

// ---------------------------------------------------------------------------
// causal depthwise conv (K=3) + bias + SiLU -> xc; silu(z) -> sz. float4.
// ---------------------------------------------------------------------------
__global__ __launch_bounds__(256) void conv_silu_k(
    const float* __restrict__ xz, const float* __restrict__ cw,
    const float* __restrict__ cb, float* __restrict__ xc, float* __restrict__ sz) {
  int idx = blockIdx.x * 256 + threadIdx.x;   // float4 unit: (m, d4)
  int m = idx >> 8, d4 = (idx & 255) * 4;
  int t = m & (L - 1);
  const float* base = xz + (size_t)m * (2 * DI);
  float4 r2 = *(const float4*)(base + d4);
  float4 r1 = (t >= 1) ? *(const float4*)(base - 2 * DI + d4) : make_float4(0, 0, 0, 0);
  float4 r0 = (t >= 2) ? *(const float4*)(base - 4 * DI + d4) : make_float4(0, 0, 0, 0);
  float4 zv = *(const float4*)(base + DI + d4);
  float wv[12];
  *(float4*)(wv + 0) = *(const float4*)(cw + d4 * 3 + 0);
  *(float4*)(wv + 4) = *(const float4*)(cw + d4 * 3 + 4);
  *(float4*)(wv + 8) = *(const float4*)(cw + d4 * 3 + 8);
  float4 bv = *(const float4*)(cb + d4);
  float rin0[4] = {r0.x, r0.y, r0.z, r0.w};
  float rin1[4] = {r1.x, r1.y, r1.z, r1.w};
  float rin2[4] = {r2.x, r2.y, r2.z, r2.w};
  float bb[4] = {bv.x, bv.y, bv.z, bv.w};
  float zz[4] = {zv.x, zv.y, zv.z, zv.w};
  float xo[4], zo[4];
#pragma unroll
  for (int j = 0; j < 4; ++j) {
    float v = bb[j];
    v = fmaf(rin0[j], wv[3 * j + 0], v);
    v = fmaf(rin1[j], wv[3 * j + 1], v);
    v = fmaf(rin2[j], wv[3 * j + 2], v);
    xo[j] = v * sigmoidf_(v);
    zo[j] = zz[j] * sigmoidf_(zz[j]);
  }
  *(float4*)(xc + (size_t)idx * 4) = make_float4(xo[0], xo[1], xo[2], xo[3]);
  *(float4*)(sz + (size_t)idx * 4) = make_float4(zo[0], zo[1], zo[2], zo[3]);
}

// ---------------------------------------------------------------------------
// FUSED x_proj + delta: proj dots (K split 4 ways, LDS combine) keep dtp in
// LDS, scatter B/C/lam, then compute delta = softplus(dtp@dt_w^T+dt_b) and
// write dx2 = {dlt, xt} directly (xt from the staged xs rows).
// ---------------------------------------------------------------------------
__global__ __launch_bounds__(512) void proj_delta_k(
    const float* __restrict__ xc, const float* __restrict__ xw,
    const float* __restrict__ dtw, const float* __restrict__ dtb,
    float* __restrict__ bc2f, float* __restrict__ cc2f,
    float* __restrict__ lamv, float2* __restrict__ dx2) {
  __shared__ float xs[4][DI];
  __shared__ float pt[3][4][128];
  __shared__ float dts[4][32];
  const int tid = threadIdx.x;
  const int m0 = blockIdx.x * 4;
  const int nn = tid & 127, qq = tid >> 7;
  for (int i = tid; i < 4 * DI; i += 512)
    xs[i >> 10][i & 1023] = xc[(size_t)m0 * DI + i];
  __syncthreads();
  float s0 = 0.f, s1 = 0.f, s2 = 0.f, s3 = 0.f;
  if (nn < PW) {
    const float* wr = xw + (size_t)nn * DI + qq * 256;
    const int kb = qq * 256;
#pragma unroll 4
    for (int k = 0; k < 256; k += 4) {
      float4 w4 = *(const float4*)(wr + k);
      s0 = fmaf(xs[0][kb + k], w4.x, s0); s0 = fmaf(xs[0][kb + k + 1], w4.y, s0);
      s0 = fmaf(xs[0][kb + k + 2], w4.z, s0); s0 = fmaf(xs[0][kb + k + 3], w4.w, s0);
      s1 = fmaf(xs[1][kb + k], w4.x, s1); s1 = fmaf(xs[1][kb + k + 1], w4.y, s1);
      s1 = fmaf(xs[1][kb + k + 2], w4.z, s1); s1 = fmaf(xs[1][kb + k + 3], w4.w, s1);
      s2 = fmaf(xs[2][kb + k], w4.x, s2); s2 = fmaf(xs[2][kb + k + 1], w4.y, s2);
      s2 = fmaf(xs[2][kb + k + 2], w4.z, s2); s2 = fmaf(xs[2][kb + k + 3], w4.w, s2);
      s3 = fmaf(xs[3][kb + k], w4.x, s3); s3 = fmaf(xs[3][kb + k + 1], w4.y, s3);
      s3 = fmaf(xs[3][kb + k + 2], w4.z, s3); s3 = fmaf(xs[3][kb + k + 3], w4.w, s3);
    }
    if (qq > 0) {
      pt[qq - 1][0][nn] = s0; pt[qq - 1][1][nn] = s1;
      pt[qq - 1][2][nn] = s2; pt[qq - 1][3][nn] = s3;
    }
  }
  __syncthreads();
  if (qq == 0 && nn < PW) {
    s0 += pt[0][0][nn] + pt[1][0][nn] + pt[2][0][nn];
    s1 += pt[0][1][nn] + pt[1][1][nn] + pt[2][1][nn];
    s2 += pt[0][2][nn] + pt[1][2][nn] + pt[2][2][nn];
    s3 += pt[0][3][nn] + pt[1][3][nn] + pt[2][3][nn];
    float sv[4] = {s0, s1, s2, s3};
#pragma unroll
    for (int r = 0; r < 4; ++r) {
      int m = m0 + r;
      float s = sv[r];
      if (nn < 32)        dts[r][nn] = s;
      else if (nn < 48)   bc2f[(m * 16 + nn - 32) * 2 + 0] = s;
      else if (nn < 64)   bc2f[(m * 16 + nn - 48) * 2 + 1] = s;
      else if (nn < 80)   cc2f[(m * 16 + nn - 64) * 2 + 0] = s;
      else if (nn < 96)   cc2f[(m * 16 + nn - 80) * 2 + 1] = s;
      else                lamv[m] = sigmoidf_(s);
    }
  }
  __syncthreads();
  // delta phase: each thread owns 2 consecutive d channels, all 4 rows
  {
    const int d = tid * 2;
    const float4* dtw4 = (const float4*)dtw;
    float2 bb = *(const float2*)(dtb + d);
    float a0[4], a1[4];
#pragma unroll
    for (int r = 0; r < 4; ++r) { a0[r] = bb.x; a1[r] = bb.y; }
#pragma unroll
    for (int kq = 0; kq < 8; ++kq) {
      float4 wa = dtw4[d * 8 + kq];
      float4 wb = dtw4[(d + 1) * 8 + kq];
#pragma unroll
      for (int r = 0; r < 4; ++r) {
        a0[r] = fmaf(dts[r][kq * 4 + 0], wa.x, a0[r]);
        a0[r] = fmaf(dts[r][kq * 4 + 1], wa.y, a0[r]);
        a0[r] = fmaf(dts[r][kq * 4 + 2], wa.z, a0[r]);
        a0[r] = fmaf(dts[r][kq * 4 + 3], wa.w, a0[r]);
        a1[r] = fmaf(dts[r][kq * 4 + 0], wb.x, a1[r]);
        a1[r] = fmaf(dts[r][kq * 4 + 1], wb.y, a1[r]);
        a1[r] = fmaf(dts[r][kq * 4 + 2], wb.z, a1[r]);
        a1[r] = fmaf(dts[r][kq * 4 + 3], wb.w, a1[r]);
      }
    }
#pragma unroll
    for (int r = 0; r < 4; ++r) {
      float x0 = a0[r], x1 = a1[r];
      float dl0 = (x0 > 20.f) ? x0 : log1pf(__expf(x0));
      float dl1 = (x1 > 20.f) ? x1 : log1pf(__expf(x1));
      float4 o = make_float4(dl0, xs[r][d], dl1, xs[r][d + 1]);
      *(float4*)(dx2 + (size_t)(m0 + r) * DI + d) = o;
    }
  }
}

// ---------------------------------------------------------------------------
// LDS-staged chunked scan, padded LDS (conflict-free), pass-B y epilogue.
// ---------------------------------------------------------------------------
template <bool PASS_B>
__global__ __launch_bounds__(256, 8) void scan_pass(
    const float2* __restrict__ dx2, const float* __restrict__ lamv,
    const float2* __restrict__ bc2, const float2* __restrict__ cc2,
    const float* __restrict__ sz,
    const float* __restrict__ A_log, const float* __restrict__ A_imag,
    const float* __restrict__ D_skip,
    float2* __restrict__ aggA, float2* __restrict__ aggU,
    unsigned short* __restrict__ ybuf) {
  __shared__ float4 qx[CL][17];                  // {dlt, xt, bsc, g} (padded)
  __shared__ float2 bcl[CL][17];                 // {Br, Bi}
  __shared__ float2 ccl[PASS_B ? CL : 1][17];    // {Cr, Ci}
  __shared__ float  ylds[PASS_B ? CL : 1][17];   // y per (t, ch)

  const int tid = threadIdx.x;
  const int n = tid & 15, ch = tid >> 4;
  const int bx = blockIdx.x, c = blockIdx.y;
  const int b = bx >> 6, d0 = (bx & 63) * 16;
  const int d = d0 + ch;
  const int lane = bx * 256 + tid;
  const int t0 = c * CL, mb = b * L;

  // ---- stage chunk into LDS ----
  {
    int t = tid >> 3, pr = tid & 7;              // 32 t x 8 pairs
    size_t row = (size_t)(mb + t0 + t);
    float4 v = *(const float4*)(dx2 + row * DI + d0 + pr * 2);
    float lamt = lamv[row];
    float g0 = lamt * v.x, g1 = lamt * v.z;
    qx[t][pr * 2 + 0] = make_float4(v.x, v.y, v.x - g0, g0);
    qx[t][pr * 2 + 1] = make_float4(v.z, v.w, v.z - g1, g1);
    float4 bv = *(const float4*)(bc2 + row * 16 + pr * 2);
    bcl[t][pr * 2 + 0] = make_float2(bv.x, bv.y);
    bcl[t][pr * 2 + 1] = make_float2(bv.z, bv.w);
    if constexpr (PASS_B) {
      float4 cv = *(const float4*)(cc2 + row * 16 + pr * 2);
      ccl[t][pr * 2 + 0] = make_float2(cv.x, cv.y);
      ccl[t][pr * 2 + 1] = make_float2(cv.z, cv.w);
    }
  }

  const float Ar = -__expf(A_log[d * 16 + n]);
  const float Arl = Ar * 1.44269504f;                  // * log2(e)
  const float Ai = A_imag[d * 16 + n];

  float Bxpr = 0.f, Bxpi = 0.f;
  if (c > 0) {
    float xp = dx2[(size_t)(mb + t0 - 1) * DI + d].y;
    float2 bp = bc2[(size_t)(mb + t0 - 1) * 16 + n];
    Bxpr = bp.x * xp; Bxpi = bp.y * xp;
  }
  float hr = 0.f, hi = 0.f, S = 0.f, Dsk = 0.f;
  if (PASS_B) {
    if (c > 0) {
      float2 h0 = aggU[(c - 1) * NLANES + lane];  // prefix from combine
      hr = h0.x; hi = h0.y;
    }
    Dsk = D_skip[d];
  }

  __syncthreads();

  // ---- recurrence: pure LDS + VALU ----
#pragma unroll
  for (int t = 0; t < CL; ++t) {
    float4 q = qx[t][ch];
    float2 bv = bcl[t][n];
    float ear = EXP2F(q.x * Arl);
    float sn, cs; sincos_poly(q.x * Ai, sn, cs);
    float ar = ear * cs, ai = ear * sn;
    float Bxr = bv.x * q.y, Bxi = bv.y * q.y;
    float wr = fmaf(q.z, Bxpr, hr), wi = fmaf(q.z, Bxpi, hi);
    hr = fmaf(q.w, Bxr, fmaf(-ai, wi, ar * wr));
    hi = fmaf(q.w, Bxi, fmaf(ai, wr, ar * wi));
    Bxpr = Bxr; Bxpi = Bxi;
    if constexpr (!PASS_B) {
      S += q.x;
    } else {
      float2 cv = ccl[t][n];
      float yc = fmaf(hi, cv.y, hr * cv.x);   // Re(h * conj(C))
      yc = dpp_add<0xB1>(yc);
      yc = dpp_add<0x4E>(yc);
      yc = dpp_add<0x124>(yc);
      yc = dpp_add<0x128>(yc);
      if (n == 0) ylds[t][ch] = fmaf(Dsk, q.y, yc);
    }
  }

  if constexpr (!PASS_B) {
    float earS = EXP2F(S * Arl);
    float rvS = S * Ai * 0.15915494f;     // revolutions for HW sin/cos
    float AaR = earS * COSR(rvS);
    float AaI = earS * SINR(rvS);
    int idx = c * NLANES + lane;
    aggA[idx] = make_float2(AaR, AaI);
    aggU[idx] = make_float2(hr, hi);
  } else {
    __syncthreads();
    // coalesced epilogue: y * silu(z) -> packed bf16 pairs
    int t = tid >> 3, pr = tid & 7;
    size_t row = (size_t)(mb + t0 + t);
    float2 szv = *(const float2*)(sz + row * DI + d0 + pr * 2);
    float y0 = ylds[t][pr * 2 + 0] * szv.x;
    float y1 = ylds[t][pr * 2 + 1] * szv.y;
    unsigned pk = (unsigned)f2bf(y0) | ((unsigned)f2bf(y1) << 16);
    *(unsigned*)(ybuf + row * DI + d0 + pr * 2) = pk;
  }
}

// in-place prefix: after this, aggU[c] = chunk-(c+1) entry state
__global__ __launch_bounds__(256) void scan_combine_k(
    const float2* __restrict__ aggA, float2* __restrict__ aggU) {
  int gid = blockIdx.x * 256 + threadIdx.x;
  float hr = 0.f, hi = 0.f;
#pragma unroll
  for (int c = 0; c < NCHUNK - 1; ++c) {
    float2 a = aggA[c * NLANES + gid];
    float2 u = aggU[c * NLANES + gid];
    float nr = fmaf(a.x, hr, fmaf(-a.y, hi, u.x));
    float ni = fmaf(a.x, hi, fmaf(a.y, hr, u.y));
    hr = nr; hi = ni;
    aggU[c * NLANES + gid] = make_float2(hr, hi);
  }
}

extern "C" void kernel_launch(void* const* d_in, const int* in_sizes, int n_in,
                              void* d_out, int out_size, void* d_ws, size_t ws_size,
                              hipStream_t stream) {
  const float* x        = (const float*)d_in[0];
  const float* in_proj  = (const float*)d_in[1];
  const float* conv_w   = (const float*)d_in[2];
  const float* conv_b   = (const float*)d_in[3];
  const float* x_proj_w = (const float*)d_in[4];
  const float* dt_w     = (const float*)d_in[5];
  const float* dt_b     = (const float*)d_in[6];
  const float* A_log    = (const float*)d_in[7];
  const float* A_imag   = (const float*)d_in[8];
  const float* D_skip   = (const float*)d_in[9];
  const float* out_proj = (const float*)d_in[10];
  float* out = (float*)d_out;

  float* ws = (float*)d_ws;
  float*  xz    = ws; ws += (size_t)ML * 2 * DI;                 // 16.8 MB (reused as gemm2 partials)
  float*  xc    = ws; ws += (size_t)ML * DI;                     //  8.4 MB
  float*  sz    = ws; ws += (size_t)ML * DI;                     //  8.4 MB
  float2* dx2   = (float2*)ws; ws += (size_t)ML * DI * 2;        // 16.8 MB
  float*  bc2f  = ws; ws += (size_t)ML * 32;                     // float2[ML*16]
  float*  cc2f  = ws; ws += (size_t)ML * 32;
  float*  lamv  = ws; ws += ML;
  float2* aggA  = (float2*)ws; ws += (size_t)NCHUNK * NLANES * 2; // 8.4 MB
  float2* aggU  = (float2*)ws; ws += (size_t)NCHUNK * NLANES * 2; // 8.4 MB
  unsigned short* xb   = (unsigned short*)ws; ws += (size_t)ML * DM / 2;
  unsigned short* wb1  = (unsigned short*)ws; ws += (size_t)(2 * DI) * DM / 2;
  unsigned short* wb2  = (unsigned short*)ws; ws += (size_t)DM * DI / 2;
  unsigned short* ybuf = (unsigned short*)ws; ws += (size_t)ML * DI / 2;

  const int n0 = ML * DM / 4, n1 = 2 * DI * DM / 4, n2 = DM * DI / 4;
  cvt3_k<<<(n0 + n1 + n2 + 255) / 256, 256, 0, stream>>>(x, xb, n0, in_proj, wb1, n1,
                                                         out_proj, wb2, n2);
  gemm_bf16_64<<<dim3(2 * DI / 64, ML / 64), 256, 0, stream>>>(
      (const short*)xb, (const short*)wb1, xz, ML, 2 * DI, DM);
  conv_silu_k<<<ML * DI / 4 / 256, 256, 0, stream>>>(xz, conv_w, conv_b, xc, sz);
  proj_delta_k<<<ML / 4, 512, 0, stream>>>(xc, x_proj_w, dt_w, dt_b,
                                           bc2f, cc2f, lamv, dx2);
  scan_pass<false><<<dim3(128, NCHUNK - 1), 256, 0, stream>>>(
      dx2, lamv, (const float2*)bc2f, (const float2*)cc2f, sz,
      A_log, A_imag, D_skip, aggA, aggU, nullptr);
  scan_combine_k<<<NLANES / 256, 256, 0, stream>>>(aggA, aggU);
  scan_pass<true><<<dim3(128, NCHUNK), 256, 0, stream>>>(
      dx2, lamv, (const float2*)bc2f, (const float2*)cc2f, sz,
      A_log, A_imag, D_skip, aggA, aggU, ybuf);
  // gemm2 split-K=4 into partials (reusing dead xz buffer), then reduce
  gemm_bf16_64_sk<<<dim3(DM / 64, ML / 64, 4), 256, 0, stream>>>(
      (const short*)ybuf, (const short*)wb2, xz, ML, DM, DI);
  addp4_k<<<ML * DM / 4 / 256, 256, 0, stream>>>((const float4*)xz, (float4*)out);
}